// Round 1
// baseline (133.835 us; speedup 1.0000x reference)
//
#include <hip/hip_runtime.h>

typedef float f32x4 __attribute__((ext_vector_type(4)));
typedef short bf16x8 __attribute__((ext_vector_type(8)));

#define N_TOTAL 8192
#define N_SRC   4096
#define DDIM    256
#define LOG2E   1.4426950408889634f

__device__ __forceinline__ unsigned short f2bf(float f) {
  return __builtin_bit_cast(unsigned short, (__bf16)f);
}

// ---------------------------------------------------------------------------
// K1: per-row sum of squares (f32) + cast rows to bf16 cache; block 0 zeroes colsum
// grid 2048 x 256 : 4 rows per block (1 wave per row)
// ---------------------------------------------------------------------------
__global__ __launch_bounds__(256) void k_sq_cast(
    const float* __restrict__ src, const float* __restrict__ tgt,
    float* __restrict__ sq, unsigned short* __restrict__ Vbf,
    float* __restrict__ colsum) {
  const int t = threadIdx.x;
  const int lane = t & 63;
  const int w = t >> 6;
  const int row = blockIdx.x * 4 + w;
  const float* rowp = (row < N_SRC) ? (src + (size_t)row * DDIM)
                                    : (tgt + (size_t)(row - N_SRC) * DDIM);
  float4 v = ((const float4*)rowp)[lane];   // 4 consecutive f32 per lane
  float ss = v.x * v.x + v.y * v.y + v.z * v.z + v.w * v.w;
  #pragma unroll
  for (int m = 32; m >= 1; m >>= 1) ss += __shfl_xor(ss, m, 64);
  if (lane == 0) sq[row] = ss;
  ushort4 p;
  p.x = f2bf(v.x); p.y = f2bf(v.y); p.z = f2bf(v.z); p.w = f2bf(v.w);
  ((ushort4*)Vbf)[(size_t)row * 64 + lane] = p;
  if (blockIdx.x == 0) colsum[t] = 0.0f;    // zeroed before K2 runs (stream order)
}

// ---------------------------------------------------------------------------
// K2: column sums of concat(src,tgt) in f32. grid 64 x 256, 128 rows per block.
// ---------------------------------------------------------------------------
__global__ __launch_bounds__(256) void k_colsum(
    const float* __restrict__ src, const float* __restrict__ tgt,
    float* __restrict__ colsum) {
  const int t = threadIdx.x;
  const int b = blockIdx.x;
  const float* base = (b < 32) ? (src + (size_t)b * 128 * DDIM)
                               : (tgt + (size_t)(b - 32) * 128 * DDIM);
  float p = 0.0f;
  for (int r = 0; r < 128; ++r) p += base[(size_t)r * DDIM + t];
  atomicAdd(colsum + t, p);
}

// ---------------------------------------------------------------------------
// K3: bandwidth via closed form: sum_l2 = 2*n*S - 2*||colsum||^2.
// Writes nc0 = -log2(e)/bandwidth ; zeroes the double accumulator.
// ---------------------------------------------------------------------------
__global__ __launch_bounds__(256) void k_bw(
    const float* __restrict__ sq, const float* __restrict__ colsum,
    float* __restrict__ nc0, double* __restrict__ accum) {
  const int t = threadIdx.x;
  const int lane = t & 63;
  const int w = t >> 6;
  float sp = 0.0f;
  for (int i = t; i < N_TOTAL; i += 256) sp += sq[i];
  float c = colsum[t];
  float cp = c * c;
  #pragma unroll
  for (int m = 32; m >= 1; m >>= 1) {
    sp += __shfl_xor(sp, m, 64);
    cp += __shfl_xor(cp, m, 64);
  }
  __shared__ float red[8];
  if (lane == 0) { red[w] = sp; red[4 + w] = cp; }
  __syncthreads();
  if (t == 0) {
    float S   = red[0] + red[1] + red[2] + red[3];
    float CSQ = red[4] + red[5] + red[6] + red[7];
    float sum_l2 = 2.0f * (float)N_TOTAL * S - 2.0f * CSQ;
    float bw = sum_l2 / ((float)N_TOTAL * (float)N_TOTAL - (float)N_TOTAL) / 4.0f;
    *nc0 = -LOG2E / bw;
    *accum = 0.0;
  }
}

// ---------------------------------------------------------------------------
// K4: main — tiled bf16 MFMA Gram + fused 5-kernel gaussian sum + signed reduce.
// 128x128 tile, 4 waves (2x2), BK=64, K=256 (4 k-steps).
// Upper-triangular tiles only; off-diagonal doubled by symmetry.
// LDS XOR-swizzle (byte ^= (row&7)<<4) applied on write AND read.
// ---------------------------------------------------------------------------
__global__ __launch_bounds__(256) void k_main(
    const unsigned short* __restrict__ Vbf, const float* __restrict__ sq,
    const float* __restrict__ nc0p, double* __restrict__ accum) {
  const int bcol = blockIdx.x;
  const int brow = blockIdx.y;
  if (bcol < brow) return;   // symmetry: upper triangle only

  const int t = threadIdx.x;
  const int lane = t & 63;
  const int w = t >> 6;
  const int wr = w >> 1;     // wave row 0..1
  const int wc = w & 1;      // wave col 0..1
  const int i0 = brow * 128;
  const int j0 = bcol * 128;

  __shared__ uint4 lds4[2048];           // 32 KB: A tile 16KB then B tile 16KB
  char* As = (char*)lds4;
  char* Bs = (char*)lds4 + 16384;

  const unsigned short* VA = Vbf + (size_t)i0 * DDIM;
  const unsigned short* VB = Vbf + (size_t)j0 * DDIM;

  f32x4 acc[4][4] = {};

  const int srow = t >> 3;               // 0..31 (row within 32-row staging chunk)
  const int scb  = (t & 7) * 16;         // byte offset within 128B row

  for (int ks = 0; ks < 4; ++ks) {
    const int kc = ks * 64;              // element k base
    __syncthreads();
    // ---- stage A,B k-slab into LDS (reg-staged, swizzled write position) ----
    #pragma unroll
    for (int it = 0; it < 4; ++it) {
      const int r = it * 32 + srow;                     // 0..127
      const int dst = r * 128 + (scb ^ ((r & 7) << 4)); // swizzled byte pos
      uint4 ga = *(const uint4*)(VA + (size_t)r * DDIM + kc + (scb >> 1));
      uint4 gb = *(const uint4*)(VB + (size_t)r * DDIM + kc + (scb >> 1));
      *(uint4*)(As + dst) = ga;
      *(uint4*)(Bs + dst) = gb;
    }
    __syncthreads();
    // ---- compute: 2 sub-steps of k=32, 16 MFMAs each ----
    #pragma unroll
    for (int kk = 0; kk < 2; ++kk) {
      const int kbyte = kk * 64 + ((lane >> 4) << 4);   // 16B-aligned k offset
      bf16x8 a[4], b[4];
      #pragma unroll
      for (int m = 0; m < 4; ++m) {
        const int ra = wr * 64 + m * 16 + (lane & 15);
        a[m] = *(const bf16x8*)(As + ra * 128 + (kbyte ^ ((ra & 7) << 4)));
        const int rb = wc * 64 + m * 16 + (lane & 15);
        b[m] = *(const bf16x8*)(Bs + rb * 128 + (kbyte ^ ((rb & 7) << 4)));
      }
      #pragma unroll
      for (int m = 0; m < 4; ++m)
        #pragma unroll
        for (int n = 0; n < 4; ++n)
          acc[m][n] = __builtin_amdgcn_mfma_f32_16x16x32_bf16(a[m], b[n], acc[m][n], 0, 0, 0);
    }
  }

  // ---- epilogue: l2 -> 5x exp2 -> signed sum ----
  const float nc0 = *nc0p;
  float rsv[16];
  const int rbase = i0 + wr * 64 + ((lane >> 4) << 2);
  #pragma unroll
  for (int m = 0; m < 4; ++m) {
    const float4 q = *(const float4*)(sq + rbase + m * 16);
    rsv[m * 4 + 0] = q.x; rsv[m * 4 + 1] = q.y;
    rsv[m * 4 + 2] = q.z; rsv[m * 4 + 3] = q.w;
  }
  float cs[4];
  const int cbase = j0 + wc * 64 + (lane & 15);
  #pragma unroll
  for (int n = 0; n < 4; ++n) cs[n] = sq[cbase + n * 16];

  float ksum = 0.0f;
  #pragma unroll
  for (int m = 0; m < 4; ++m)
    #pragma unroll
    for (int n = 0; n < 4; ++n)
      #pragma unroll
      for (int r = 0; r < 4; ++r) {
        const float g  = acc[m][n][r];
        const float l2 = fmaxf(fmaf(-2.0f, g, rsv[m * 4 + r]) + cs[n], 0.0f);
        const float tt = l2 * nc0;   // = -l2*log2(e)/bw  (<= 0)
        ksum += __builtin_amdgcn_exp2f(tt)
              + __builtin_amdgcn_exp2f(tt * 0.5f)
              + __builtin_amdgcn_exp2f(tt * 0.25f)
              + __builtin_amdgcn_exp2f(tt * 0.125f)
              + __builtin_amdgcn_exp2f(tt * 0.0625f);
      }

  // wave reduce, then block reduce, then one atomic per block
  #pragma unroll
  for (int m = 32; m >= 1; m >>= 1) ksum += __shfl_xor(ksum, m, 64);
  __shared__ float red[4];
  if (lane == 0) red[w] = ksum;
  __syncthreads();
  if (t == 0) {
    // sign: (+1) for xx/yy quadrants, (-1) for xy/yx; x2 for off-diagonal tiles
    const float sign = ((brow < 32) == (bcol < 32)) ? 1.0f : -1.0f;
    const float mult = (brow == bcol) ? 1.0f : 2.0f;
    const double contrib = (double)((red[0] + red[1] + red[2] + red[3]) * sign * mult);
    atomicAdd(accum, contrib);
  }
}

// ---------------------------------------------------------------------------
// K5: final normalization: / 4096^2
// ---------------------------------------------------------------------------
__global__ void k_final(const double* __restrict__ accum, float* __restrict__ out) {
  out[0] = (float)(accum[0] * (1.0 / 16777216.0));
}

// ---------------------------------------------------------------------------
extern "C" void kernel_launch(void* const* d_in, const int* in_sizes, int n_in,
                              void* d_out, int out_size, void* d_ws, size_t ws_size,
                              hipStream_t stream) {
  const float* src = (const float*)d_in[0];
  const float* tgt = (const float*)d_in[1];
  char* ws = (char*)d_ws;
  double* accum          = (double*)ws;                       // 8 B
  float*  nc0            = (float*)(ws + 8);                  // 4 B
  float*  colsum         = (float*)(ws + 64);                 // 1 KB
  float*  sq             = (float*)(ws + 2048);               // 32 KB
  unsigned short* Vbf    = (unsigned short*)(ws + 65536);     // 4 MB bf16 cache
  float* out = (float*)d_out;

  hipLaunchKernelGGL(k_sq_cast, dim3(2048), dim3(256), 0, stream, src, tgt, sq, Vbf, colsum);
  hipLaunchKernelGGL(k_colsum,  dim3(64),   dim3(256), 0, stream, src, tgt, colsum);
  hipLaunchKernelGGL(k_bw,      dim3(1),    dim3(256), 0, stream, sq, colsum, nc0, accum);
  hipLaunchKernelGGL(k_main,    dim3(64, 64), dim3(256), 0, stream, Vbf, sq, nc0, accum);
  hipLaunchKernelGGL(k_final,   dim3(1),    dim3(1),   0, stream, accum, out);
}